// Round 14
// baseline (83.046 us; speedup 1.0000x reference)
//
#include <hip/hip_runtime.h>
#include <hip/hip_bf16.h>
#include <math.h>

#define T_TOK 4096
#define D_MODEL 1024
#define L_LAT 256
#define H_HID 512
#define E_EXP 8
#define SH_HID 512
#define TOT_EROWS (2 * T_TOK)

typedef __bf16 bf16x8 __attribute__((ext_vector_type(8)));
typedef float f32x4 __attribute__((ext_vector_type(4)));

__device__ __forceinline__ unsigned short f2bf(float f) {
    union { float f; unsigned int u; } c{f};
    unsigned int r = (c.u + 0x7fffu + ((c.u >> 16) & 1u)) >> 16;
    return (unsigned short)r;
}
__device__ __forceinline__ float bf2f(unsigned short u) {
    union { unsigned int u; float f; } c{(unsigned int)u << 16};
    return c.f;
}

__device__ __forceinline__ void gload_lds16(const unsigned short* g, unsigned short* l) {
    __builtin_amdgcn_global_load_lds(
        (const __attribute__((address_space(1))) void*)g,
        (__attribute__((address_space(3))) void*)l,
        16, 0, 0);
}

// 3-bit XOR slot swizzle for BK=64 rows (8 slots x 8 bf16 = 128 B row). Involution.
__device__ __forceinline__ int swz64(int row, int s) {
    return s ^ (row & 7);
}

// ================= D1: fused router+x-cast + small-weight casts (jobs) ===========
// [0,1024): router + x->bf16 cast (1 block = 4 tokens); [1024,2304): wdown/wgs/w1s
__global__ __launch_bounds__(256)
void cast_router_kernel(const float* __restrict__ x, const float* __restrict__ w_router,
                        const float* __restrict__ w_down, const float* __restrict__ wg_s,
                        const float* __restrict__ w1_s,
                        unsigned short* __restrict__ xb, unsigned short* __restrict__ wdb,
                        unsigned short* __restrict__ wgsb, unsigned short* __restrict__ w1sb,
                        int* __restrict__ topk_idx, float* __restrict__ topk_w)
{
    __shared__ float wlds[E_EXP * D_MODEL];   // 32 KB (router job only)
    int bid = blockIdx.x;
    int tid = threadIdx.x;

    if (bid >= 1024) {
        int i = (bid - 1024) * 256 + tid;      // [0, 327680) float4s
        const float* src; unsigned short* dst; int base;
        if      (i < 65536)  { src = w_down; dst = wdb;  base = 0; }
        else if (i < 196608) { src = wg_s;   dst = wgsb; base = 65536; }
        else                 { src = w1_s;   dst = w1sb; base = 196608; }
        int j = (i - base) * 4;
        float4 v = *(const float4*)(src + j);
        ushort4 o = { f2bf(v.x), f2bf(v.y), f2bf(v.z), f2bf(v.w) };
        *(ushort4*)(dst + j) = o;
        return;
    }

    // ---- fused router (exact fp32) + x-cast: wave w handles token bid*4+w ----
    for (int i = tid * 4; i < E_EXP * D_MODEL; i += 256 * 4)
        *(float4*)(wlds + i) = *(const float4*)(w_router + i);
    __syncthreads();

    int wid = tid >> 6, lane = tid & 63;
    int t = bid * 4 + wid;
    const float4* xr4 = (const float4*)(x + (size_t)t * D_MODEL);
    ushort4* xb4 = (ushort4*)(xb + (size_t)t * D_MODEL);
    const float4* wl4 = (const float4*)wlds;

    float acc[E_EXP];
#pragma unroll
    for (int e = 0; e < E_EXP; ++e) acc[e] = 0.f;
#pragma unroll
    for (int j = 0; j < 4; ++j) {
        int f = lane + 64 * j;
        float4 v = xr4[f];
        ushort4 o = { f2bf(v.x), f2bf(v.y), f2bf(v.z), f2bf(v.w) };
        xb4[f] = o;
#pragma unroll
        for (int e = 0; e < E_EXP; ++e) {
            float4 w = wl4[e * 256 + f];
            acc[e] += v.x * w.x + v.y * w.y + v.z * w.z + v.w * w.w;
        }
    }
#pragma unroll
    for (int e = 0; e < E_EXP; ++e)
        for (int off = 32; off > 0; off >>= 1)
            acc[e] += __shfl_xor(acc[e], off, 64);
    if (lane == 0) {
        int i0 = 0; float v0 = acc[0];
#pragma unroll
        for (int e = 1; e < E_EXP; ++e) if (acc[e] > v0) { v0 = acc[e]; i0 = e; }
        int i1 = -1; float v1 = -INFINITY;
#pragma unroll
        for (int e = 0; e < E_EXP; ++e) if (e != i0 && acc[e] > v1) { v1 = acc[e]; i1 = e; }
        float e1 = expf(v1 - v0);
        topk_idx[2 * t] = i0; topk_idx[2 * t + 1] = i1;
        topk_w[2 * t] = 1.f / (1.f + e1);
        topk_w[2 * t + 1] = e1 / (1.f + e1);
    }
}

// ================= bucket body (deterministic, no atomics; 256 threads) =========
__device__ void bucket_body(const int* __restrict__ topk_idx,
                            int* __restrict__ counts, int* __restrict__ offsets,
                            int* __restrict__ tok_of_row, int* __restrict__ row_of_pair,
                            int* sb)
{
    int* s_wavecnt  = sb;        // [4][8]
    int* s_wavebase = sb + 32;   // [4][8]
    int* s_tot      = sb + 64;   // [8]
    int* s_off      = sb + 72;   // [8]
    int tid = threadIdx.x, wave = tid >> 6, lane = tid & 63;
    int base_i = tid * 32;       // 8192 items / 256 threads

    int cnt[E_EXP];
#pragma unroll
    for (int e = 0; e < E_EXP; ++e) cnt[e] = 0;
#pragma unroll
    for (int j = 0; j < 32; ++j) {
        int e = topk_idx[base_i + j];
#pragma unroll
        for (int q = 0; q < E_EXP; ++q) cnt[q] += (e == q) ? 1 : 0;
    }
    int excl[E_EXP];
#pragma unroll
    for (int e = 0; e < E_EXP; ++e) {
        int v = cnt[e];
#pragma unroll
        for (int off = 1; off < 64; off <<= 1) {
            int u = __shfl_up(v, off, 64);
            v += (lane >= off) ? u : 0;
        }
        excl[e] = v - cnt[e];
        if (lane == 63) s_wavecnt[wave * 8 + e] = v;
    }
    __syncthreads();
    if (tid < E_EXP) {
        int tot = 0;
        for (int w = 0; w < 4; ++w) tot += s_wavecnt[w * 8 + tid];
        s_tot[tid] = tot;
        counts[tid] = tot;
    }
    __syncthreads();
    if (tid == 0) {
        int off = 0;
        for (int e = 0; e < E_EXP; ++e) { s_off[e] = off; offsets[e] = off; off += s_tot[e]; }
    }
    __syncthreads();
    if (tid < E_EXP) {
        int run = s_off[tid];
        for (int w = 0; w < 4; ++w) { s_wavebase[w * 8 + tid] = run; run += s_wavecnt[w * 8 + tid]; }
    }
    __syncthreads();
    int tb[E_EXP];
#pragma unroll
    for (int e = 0; e < E_EXP; ++e) tb[e] = s_wavebase[wave * 8 + e] + excl[e];
#pragma unroll
    for (int j = 0; j < 32; ++j) {
        int item = base_i + j;
        int e = topk_idx[item];
        int p = 0;
#pragma unroll
        for (int q = 0; q < E_EXP; ++q) if (e == q) { p = tb[q]; tb[q] = p + 1; }
        tok_of_row[p] = item >> 1;
        row_of_pair[item] = p;
    }
}

// ================= proven BK=64 BN=64 GEMM tile body (dual-capable) =============
// OUT_MODE: 0 = f32 store, 1 = bf16 store
template<bool DUAL, bool SILU, bool EXPERT, bool GATHER, int OUT_MODE>
__device__ void gemm_tile(unsigned short* As, unsigned short* Bs0, unsigned short* Bs1,
                          int m0, int n0, int e,
                          const unsigned short* __restrict__ A,
                          const unsigned short* __restrict__ B0g,
                          const unsigned short* __restrict__ B1g,
                          void* __restrict__ Cv,
                          int M, int K, int ldc,
                          const int* __restrict__ tok_of_row,
                          const int* __restrict__ offsets,
                          const int* __restrict__ counts,
                          long strideB)
{
    int m_base = EXPERT ? offsets[e] : 0;
    int m_count = EXPERT ? counts[e] : M;
    if (m0 >= m_count) return;   // block-uniform

    const unsigned short* B0 = B0g + (EXPERT ? (size_t)e * strideB : 0);
    const unsigned short* B1 = DUAL ? (B1g + (EXPERT ? (size_t)e * strideB : 0)) : nullptr;

    int tid = threadIdx.x;
    int r8 = tid >> 3, slot = tid & 7;

    const unsigned short* aptr[4];
#pragma unroll
    for (int r = 0; r < 4; ++r) {
        int rl = r * 32 + r8;
        int mrow = m0 + rl;
        if (mrow >= m_count) mrow = m_count - 1;      // clamp (epilogue masks)
        long grow;
        if (GATHER)      grow = tok_of_row[m_base + mrow];
        else if (EXPERT) grow = m_base + mrow;
        else             grow = mrow;
        aptr[r] = A + (size_t)grow * K + swz64(rl, slot) * 8;
    }
    const unsigned short* bptr0[2];
    const unsigned short* bptr1[2];
#pragma unroll
    for (int r = 0; r < 2; ++r) {
        int rl = r * 32 + r8;
        int gs = swz64(rl, slot) * 8;
        bptr0[r] = B0 + (size_t)(n0 + rl) * K + gs;
        if (DUAL) bptr1[r] = B1 + (size_t)(n0 + rl) * K + gs;
    }
    unsigned short* As_dst  = As  + tid * 8;
    unsigned short* Bs0_dst = Bs0 + tid * 8;
    unsigned short* Bs1_dst = DUAL ? (Bs1 + tid * 8) : nullptr;

    int wave = tid >> 6, lane = tid & 63;
    int wm0 = (wave >> 1) * 64, wn0 = (wave & 1) * 32;
    int l15 = lane & 15, kg = lane >> 4;

    f32x4 acc0[4][2] = {};
    f32x4 acc1[DUAL ? 4 : 1][DUAL ? 2 : 1] = {};

    for (int k0 = 0; k0 < K; k0 += 64) {
#pragma unroll
        for (int r = 0; r < 4; ++r)
            gload_lds16(aptr[r] + k0, As_dst + r * 2048);
#pragma unroll
        for (int r = 0; r < 2; ++r) {
            gload_lds16(bptr0[r] + k0, Bs0_dst + r * 2048);
            if constexpr (DUAL) gload_lds16(bptr1[r] + k0, Bs1_dst + r * 2048);
        }
        __syncthreads();

        bf16x8 af[2][4];
#pragma unroll
        for (int kh = 0; kh < 2; ++kh)
#pragma unroll
            for (int mf = 0; mf < 4; ++mf) {
                int row = wm0 + mf * 16 + l15;
                af[kh][mf] = *reinterpret_cast<const bf16x8*>(As + row * 64 + swz64(row, kh * 4 + kg) * 8);
            }
        bf16x8 bf0[2][2], bf1[2][2];
#pragma unroll
        for (int kh = 0; kh < 2; ++kh)
#pragma unroll
            for (int nf = 0; nf < 2; ++nf) {
                int row = wn0 + nf * 16 + l15;
                bf0[kh][nf] = *reinterpret_cast<const bf16x8*>(Bs0 + row * 64 + swz64(row, kh * 4 + kg) * 8);
                if constexpr (DUAL)
                    bf1[kh][nf] = *reinterpret_cast<const bf16x8*>(Bs1 + row * 64 + swz64(row, kh * 4 + kg) * 8);
            }
#pragma unroll
        for (int kh = 0; kh < 2; ++kh)
#pragma unroll
            for (int mf = 0; mf < 4; ++mf)
#pragma unroll
                for (int nf = 0; nf < 2; ++nf) {
                    acc0[mf][nf] = __builtin_amdgcn_mfma_f32_16x16x32_bf16(af[kh][mf], bf0[kh][nf], acc0[mf][nf], 0, 0, 0);
                    if constexpr (DUAL)
                        acc1[mf][nf] = __builtin_amdgcn_mfma_f32_16x16x32_bf16(af[kh][mf], bf1[kh][nf], acc1[mf][nf], 0, 0, 0);
                }
        __syncthreads();
    }

#pragma unroll
    for (int mf = 0; mf < 4; ++mf) {
#pragma unroll
        for (int r4 = 0; r4 < 4; ++r4) {
            int mrow = m0 + wm0 + mf * 16 + kg * 4 + r4;
            if (mrow >= m_count) continue;
            size_t crow = (size_t)((EXPERT ? m_base : 0) + mrow) * ldc + n0 + wn0;
#pragma unroll
            for (int nf = 0; nf < 2; ++nf) {
                float v = acc0[mf][nf][r4];
                if constexpr (SILU) {
                    float g = v;
                    float a = acc1[mf][nf][r4];
                    v = (g / (1.f + expf(-g))) * a;
                }
                int col = nf * 16 + l15;
                if constexpr (OUT_MODE == 1) ((unsigned short*)Cv)[crow + col] = f2bf(v);
                else                         ((float*)Cv)[crow + col] = v;
            }
        }
    }
}

// ================= 128x128 non-dual tile (BK=64), gload staging ==================
// OUT_MODE: 0 = f32 store, 1 = bf16 store
template<bool EXPERT, int OUT_MODE>
__device__ void gemm_tile_n128(unsigned short* SM,
                               int m0, int n0, int e,
                               const unsigned short* __restrict__ A,
                               const unsigned short* __restrict__ B0g,
                               void* __restrict__ Cv,
                               int M, int K, int ldc,
                               const int* __restrict__ offsets,
                               const int* __restrict__ counts,
                               long strideB)
{
    unsigned short* As = SM;              // 128*64
    unsigned short* Bs = SM + 128 * 64;   // 128*64

    int m_base = EXPERT ? offsets[e] : 0;
    int m_count = EXPERT ? counts[e] : M;
    if (m0 >= m_count) return;

    const unsigned short* B0 = B0g + (EXPERT ? (size_t)e * strideB : 0);

    int tid = threadIdx.x;
    int r8 = tid >> 3, slot = tid & 7;

    const unsigned short* aptr[4];
#pragma unroll
    for (int r = 0; r < 4; ++r) {
        int rl = r * 32 + r8;
        int mrow = m0 + rl;
        if (mrow >= m_count) mrow = m_count - 1;
        long grow = EXPERT ? (long)(m_base + mrow) : (long)mrow;
        aptr[r] = A + (size_t)grow * K + swz64(rl, slot) * 8;
    }
    const unsigned short* bptr[4];
#pragma unroll
    for (int r = 0; r < 4; ++r) {
        int rl = r * 32 + r8;
        bptr[r] = B0 + (size_t)(n0 + rl) * K + swz64(rl, slot) * 8;
    }
    unsigned short* As_dst = As + tid * 8;
    unsigned short* Bs_dst = Bs + tid * 8;

    int wave = tid >> 6, lane = tid & 63;
    int wm0 = (wave >> 1) * 64, wn0 = (wave & 1) * 64;
    int l15 = lane & 15, kg = lane >> 4;

    f32x4 acc[4][4] = {};

    for (int k0 = 0; k0 < K; k0 += 64) {
#pragma unroll
        for (int r = 0; r < 4; ++r)
            gload_lds16(aptr[r] + k0, As_dst + r * 2048);
#pragma unroll
        for (int r = 0; r < 4; ++r)
            gload_lds16(bptr[r] + k0, Bs_dst + r * 2048);
        __syncthreads();

        bf16x8 af[2][4], bfr[2][4];
#pragma unroll
        for (int kh = 0; kh < 2; ++kh) {
#pragma unroll
            for (int mf = 0; mf < 4; ++mf) {
                int row = wm0 + mf * 16 + l15;
                af[kh][mf] = *reinterpret_cast<const bf16x8*>(As + row * 64 + swz64(row, kh * 4 + kg) * 8);
            }
#pragma unroll
            for (int nf = 0; nf < 4; ++nf) {
                int row = wn0 + nf * 16 + l15;
                bfr[kh][nf] = *reinterpret_cast<const bf16x8*>(Bs + row * 64 + swz64(row, kh * 4 + kg) * 8);
            }
        }
#pragma unroll
        for (int kh = 0; kh < 2; ++kh)
#pragma unroll
            for (int mf = 0; mf < 4; ++mf)
#pragma unroll
                for (int nf = 0; nf < 4; ++nf)
                    acc[mf][nf] = __builtin_amdgcn_mfma_f32_16x16x32_bf16(af[kh][mf], bfr[kh][nf], acc[mf][nf], 0, 0, 0);
        __syncthreads();
    }

#pragma unroll
    for (int mf = 0; mf < 4; ++mf) {
#pragma unroll
        for (int r4 = 0; r4 < 4; ++r4) {
            int mrow = m0 + wm0 + mf * 16 + kg * 4 + r4;
            if (mrow >= m_count) continue;
            size_t crow = (size_t)((EXPERT ? m_base : 0) + mrow) * ldc + n0 + wn0;
#pragma unroll
            for (int nf = 0; nf < 4; ++nf) {
                float v = acc[mf][nf][r4];
                int col = nf * 16 + l15;
                if constexpr (OUT_MODE == 1) ((unsigned short*)Cv)[crow + col] = f2bf(v);
                else                         ((float*)Cv)[crow + col] = v;
            }
        }
    }
}

// ================= D2: GEMM2 + GEMM1 + bucket + big-weight casts (jobs) ==========
// [0,256): GEMM2 (dual, largest tiles first); [256,384): GEMM1; ==384: bucket;
// (384,4225): casts wge/w1e/w2e/w_up/w2_s
__global__ __launch_bounds__(256)
void k_main(const unsigned short* __restrict__ x_bf,
            const unsigned short* __restrict__ wdown_bf,
            const unsigned short* __restrict__ wgs_bf,
            const unsigned short* __restrict__ w1s_bf,
            const float* __restrict__ wg_e, const float* __restrict__ w1_e,
            const float* __restrict__ w2_e,
            const float* __restrict__ w_up, const float* __restrict__ w2_s,
            unsigned short* __restrict__ lat_bf,
            unsigned short* __restrict__ hs,
            unsigned short* __restrict__ wge_bf, unsigned short* __restrict__ w1e_bf,
            unsigned short* __restrict__ w2e_bf, unsigned short* __restrict__ wup_bf,
            unsigned short* __restrict__ w2s_bf,
            const int* __restrict__ topk_idx,
            int* __restrict__ counts, int* __restrict__ offsets,
            int* __restrict__ tok_of_row, int* __restrict__ row_of_pair)
{
    __shared__ __align__(16) unsigned short SM[16384];   // 32 KB
    unsigned short* As  = SM;
    unsigned short* Bs0 = SM + 8192;
    unsigned short* Bs1 = SM + 12288;

    int bid = blockIdx.x;
    int tid = threadIdx.x;

    if (bid == 384) {
        bucket_body(topk_idx, counts, offsets, tok_of_row, row_of_pair, (int*)SM);
        return;
    }
    if (bid > 384) {
        int i = (bid - 385) * 256 + tid;       // [0, 983040) float4s
        const float* src; unsigned short* dst; int base;
        if      (i < 262144) { src = wg_e; dst = wge_bf; base = 0; }
        else if (i < 524288) { src = w1_e; dst = w1e_bf; base = 262144; }
        else if (i < 786432) { src = w2_e; dst = w2e_bf; base = 524288; }
        else if (i < 851968) { src = w_up; dst = wup_bf; base = 786432; }
        else                 { src = w2_s; dst = w2s_bf; base = 851968; }
        int j = (i - base) * 4;
        float4 v = *(const float4*)(src + j);
        ushort4 o = { f2bf(v.x), f2bf(v.y), f2bf(v.z), f2bf(v.w) };
        *(ushort4*)(dst + j) = o;
        return;
    }

    if (bid < 256) {
        // GEMM2 (dual-silu, K=1024): biggest tiles first
        int xq = bid & 31, y = bid >> 5;   // y in [0,8)
        gemm_tile<true, true, false, false, 1>(As, Bs0, Bs1, xq * 128, y * 64, 0,
            x_bf, wgs_bf, w1s_bf, hs, T_TOK, D_MODEL, SH_HID,
            nullptr, nullptr, nullptr, 0);
    } else {
        int idx = bid - 256;
        int xq = idx & 31, y = idx >> 5;   // y in [0,4)
        gemm_tile<false, false, false, false, 1>(As, Bs0, Bs1, xq * 128, y * 64, 0,
            x_bf, wdown_bf, nullptr, lat_bf, T_TOK, D_MODEL, L_LAT,
            nullptr, nullptr, nullptr, 0);
    }
}

// ================= D3: shared out (BN=128, first) + expert-up (BN=64 dual) =======
// [0,256): out_s = hs @ w2_s^T -> outs (bf16); [256,4352): expert-up (early-exit)
__global__ __launch_bounds__(256)
void k_exp_sh(const unsigned short* __restrict__ lat_bf,
              const unsigned short* __restrict__ wge_bf,
              const unsigned short* __restrict__ w1e_bf,
              const unsigned short* __restrict__ hs,
              const unsigned short* __restrict__ w2s_bf,
              unsigned short* __restrict__ hbuf_bf,
              unsigned short* __restrict__ outs,
              const int* __restrict__ tok_of_row,
              const int* __restrict__ offsets,
              const int* __restrict__ counts)
{
    __shared__ __align__(16) unsigned short SM[16384];   // 32 KB
    int bid = blockIdx.x;
    if (bid < 256) {
        int xq = bid & 31, y = bid >> 5;     // y in [0,8)
        gemm_tile_n128<false, 1>(SM, xq * 128, y * 128, 0,
            hs, w2s_bf, outs, T_TOK, SH_HID, D_MODEL,
            nullptr, nullptr, 0);
    } else {
        int idx = bid - 256;
        int xq = idx >> 6, e = (idx >> 3) & 7, y = idx & 7;
        gemm_tile<true, true, true, true, 1>(SM, SM + 8192, SM + 12288,
            xq * 128, y * 64, e,
            lat_bf, wge_bf, w1e_bf, hbuf_bf, 0, L_LAT, H_HID,
            tok_of_row, offsets, counts, (long)H_HID * L_LAT);
    }
}

// ================= D4: expert-down -> ex_bf (BM=128/BN=64, 256 active blocks) ====
__global__ __launch_bounds__(256)
void k_expdown(const unsigned short* __restrict__ hbuf_bf,
               const unsigned short* __restrict__ w2e_bf,
               unsigned short* __restrict__ ex_bf,
               const int* __restrict__ offsets,
               const int* __restrict__ counts)
{
    __shared__ __align__(16) unsigned short SM[16384];
    gemm_tile<false, false, true, false, 1>(SM, SM + 8192, SM + 12288,
        blockIdx.x * 128, blockIdx.y * 64, blockIdx.z,
        hbuf_bf, w2e_bf, nullptr, ex_bf, 0, H_HID, L_LAT,
        nullptr, offsets, counts, (long)L_LAT * H_HID);
}

// ================= D5: out = combine(ex)@w_up^T + outs  (BM=128/BN=64) ==========
// A: reg-blend staged (uniform every K-step); B: gload_lds (uniform every K-step)
__global__ __launch_bounds__(256)
void k_final(const unsigned short* __restrict__ ex_bf,
             const unsigned short* __restrict__ wup_bf,
             const unsigned short* __restrict__ outs,
             const int* __restrict__ row_of_pair,
             const float* __restrict__ topk_w,
             float* __restrict__ out)
{
    __shared__ __align__(16) unsigned short As[128 * 64];   // 16 KB
    __shared__ __align__(16) unsigned short Bs[64 * 64];    // 8 KB

    int m0 = blockIdx.x * 128, n0 = blockIdx.y * 64;
    int tid = threadIdx.x;
    int r8 = tid >> 3, slot = tid & 7;

    const unsigned short* aptr[4];
    const unsigned short* a2ptr[4];
    float wa[4], wb[4];
#pragma unroll
    for (int r = 0; r < 4; ++r) {
        int rl = r * 32 + r8;
        int t = m0 + rl;
        int rp0 = row_of_pair[2 * t], rp1 = row_of_pair[2 * t + 1];
        wa[r] = topk_w[2 * t]; wb[r] = topk_w[2 * t + 1];
        int gs = swz64(rl, slot) * 8;
        aptr[r]  = ex_bf + (size_t)rp0 * L_LAT + gs;
        a2ptr[r] = ex_bf + (size_t)rp1 * L_LAT + gs;
    }
    const unsigned short* bptr[2];
#pragma unroll
    for (int r = 0; r < 2; ++r) {
        int rl = r * 32 + r8;
        bptr[r] = wup_bf + (size_t)(n0 + rl) * L_LAT + swz64(rl, slot) * 8;
    }
    unsigned short* As_dst = As + tid * 8;
    unsigned short* Bs_dst = Bs + tid * 8;

    int wave = tid >> 6, lane = tid & 63;
    int wm0 = (wave >> 1) * 64, wn0 = (wave & 1) * 32;
    int l15 = lane & 15, kg = lane >> 4;

    f32x4 acc[4][2] = {};

    for (int k0 = 0; k0 < L_LAT; k0 += 64) {
        // A: reg-blend stage (uniform mechanism every step)
#pragma unroll
        for (int r = 0; r < 4; ++r) {
            ushort4 u0 = *(const ushort4*)(aptr[r] + k0);
            ushort4 u1 = *(const ushort4*)(aptr[r] + k0 + 4);
            ushort4 v0 = *(const ushort4*)(a2ptr[r] + k0);
            ushort4 v1 = *(const ushort4*)(a2ptr[r] + k0 + 4);
            ushort4 lo = { f2bf(wa[r] * bf2f(u0.x) + wb[r] * bf2f(v0.x)),
                           f2bf(wa[r] * bf2f(u0.y) + wb[r] * bf2f(v0.y)),
                           f2bf(wa[r] * bf2f(u0.z) + wb[r] * bf2f(v0.z)),
                           f2bf(wa[r] * bf2f(u0.w) + wb[r] * bf2f(v0.w)) };
            ushort4 hi = { f2bf(wa[r] * bf2f(u1.x) + wb[r] * bf2f(v1.x)),
                           f2bf(wa[r] * bf2f(u1.y) + wb[r] * bf2f(v1.y)),
                           f2bf(wa[r] * bf2f(u1.z) + wb[r] * bf2f(v1.z)),
                           f2bf(wa[r] * bf2f(u1.w) + wb[r] * bf2f(v1.w)) };
            *(ushort4*)(As_dst + r * 2048) = lo;
            *(ushort4*)(As_dst + r * 2048 + 4) = hi;
        }
        // B: gload stage (uniform mechanism every step)
#pragma unroll
        for (int r = 0; r < 2; ++r)
            gload_lds16(bptr[r] + k0, Bs_dst + r * 2048);
        __syncthreads();

        bf16x8 af[2][4], bfr[2][2];
#pragma unroll
        for (int kh = 0; kh < 2; ++kh) {
#pragma unroll
            for (int mf = 0; mf < 4; ++mf) {
                int row = wm0 + mf * 16 + l15;
                af[kh][mf] = *reinterpret_cast<const bf16x8*>(As + row * 64 + swz64(row, kh * 4 + kg) * 8);
            }
#pragma unroll
            for (int nf = 0; nf < 2; ++nf) {
                int row = wn0 + nf * 16 + l15;
                bfr[kh][nf] = *reinterpret_cast<const bf16x8*>(Bs + row * 64 + swz64(row, kh * 4 + kg) * 8);
            }
        }
#pragma unroll
        for (int kh = 0; kh < 2; ++kh)
#pragma unroll
            for (int mf = 0; mf < 4; ++mf)
#pragma unroll
                for (int nf = 0; nf < 2; ++nf)
                    acc[mf][nf] = __builtin_amdgcn_mfma_f32_16x16x32_bf16(af[kh][mf], bfr[kh][nf], acc[mf][nf], 0, 0, 0);
        __syncthreads();
    }

#pragma unroll
    for (int mf = 0; mf < 4; ++mf)
#pragma unroll
        for (int r4 = 0; r4 < 4; ++r4) {
            int mrow = m0 + wm0 + mf * 16 + kg * 4 + r4;
            size_t crow = (size_t)mrow * D_MODEL + n0 + wn0;
#pragma unroll
            for (int nf = 0; nf < 2; ++nf) {
                int col = nf * 16 + l15;
                out[crow + col] = acc[mf][nf][r4] + bf2f(outs[crow + col]);
            }
        }
}

extern "C" void kernel_launch(void* const* d_in, const int* in_sizes, int n_in,
                              void* d_out, int out_size, void* d_ws, size_t ws_size,
                              hipStream_t stream)
{
    const float* x        = (const float*)d_in[0];
    const float* w_router = (const float*)d_in[1];
    const float* w_down   = (const float*)d_in[2];
    const float* w_up     = (const float*)d_in[3];
    const float* w1_e     = (const float*)d_in[4];
    const float* wg_e     = (const float*)d_in[5];
    const float* w2_e     = (const float*)d_in[6];
    const float* w1_s     = (const float*)d_in[7];
    const float* wg_s     = (const float*)d_in[8];
    const float* w2_s     = (const float*)d_in[9];
    float* out = (float*)d_out;

    char* ws = (char*)d_ws;
    size_t off = 0;
    auto alloc = [&](size_t bytes) -> void* {
        void* p = ws + off;
        off += (bytes + 255) & ~(size_t)255;
        return p;
    };
    unsigned short* x_bf    = (unsigned short*)alloc((size_t)T_TOK * D_MODEL * 2);    // 8 MB (alias: hbuf)
    unsigned short* lat_bf  = (unsigned short*)alloc((size_t)T_TOK * L_LAT * 2);      // 2 MB
    unsigned short* hs      = (unsigned short*)alloc((size_t)T_TOK * SH_HID * 2);     // 4 MB
    unsigned short* outs    = (unsigned short*)alloc((size_t)T_TOK * D_MODEL * 2);    // 8 MB
    unsigned short* ex_bf   = (unsigned short*)alloc((size_t)TOT_EROWS * L_LAT * 2);  // 4 MB
    unsigned short* wdown_bf= (unsigned short*)alloc((size_t)L_LAT * D_MODEL * 2);
    unsigned short* wge_bf  = (unsigned short*)alloc((size_t)E_EXP * H_HID * L_LAT * 2);
    unsigned short* w1e_bf  = (unsigned short*)alloc((size_t)E_EXP * H_HID * L_LAT * 2);
    unsigned short* w2e_bf  = (unsigned short*)alloc((size_t)E_EXP * L_LAT * H_HID * 2);
    unsigned short* wgs_bf  = (unsigned short*)alloc((size_t)SH_HID * D_MODEL * 2);
    unsigned short* w1s_bf  = (unsigned short*)alloc((size_t)SH_HID * D_MODEL * 2);
    unsigned short* wup_bf  = (unsigned short*)alloc((size_t)D_MODEL * L_LAT * 2);
    unsigned short* w2s_bf  = (unsigned short*)alloc((size_t)D_MODEL * SH_HID * 2);
    int*   topk_idx    = (int*)alloc(T_TOK * 2 * 4);
    float* topk_w      = (float*)alloc(T_TOK * 2 * 4);
    int*   tok_of_row  = (int*)alloc(T_TOK * 2 * 4);
    int*   row_of_pair = (int*)alloc(T_TOK * 2 * 4);
    int*   counts      = (int*)alloc(E_EXP * 4);
    int*   offsets     = (int*)alloc(E_EXP * 4);
    unsigned short* hbuf_bf = x_bf;   // alias: x_bf dead after D2

    // D1: fused router+x-cast + small-weight casts (2304 blocks)
    cast_router_kernel<<<2304, 256, 0, stream>>>(
        x, w_router, w_down, wg_s, w1_s,
        x_bf, wdown_bf, wgs_bf, w1s_bf, topk_idx, topk_w);

    // D2: GEMM2 (first) + GEMM1 + bucket + big-weight casts
    k_main<<<4225, 256, 0, stream>>>(
        x_bf, wdown_bf, wgs_bf, w1s_bf, wg_e, w1_e, w2_e, w_up, w2_s,
        lat_bf, hs, wge_bf, w1e_bf, w2e_bf, wup_bf, w2s_bf,
        topk_idx, counts, offsets, tok_of_row, row_of_pair);

    // D3: shared out-GEMM (first) + expert-up (gathered buckets)
    k_exp_sh<<<4352, 256, 0, stream>>>(
        lat_bf, wge_bf, w1e_bf, hs, w2s_bf, hbuf_bf, outs,
        tok_of_row, offsets, counts);

    // D4: expert-down: ex_bf = hbuf @ w2_e^T (BM=128/BN=64 -> 256 active blocks)
    k_expdown<<<dim3(TOT_EROWS / 128, L_LAT / 64, E_EXP), 256, 0, stream>>>(
        hbuf_bf, w2e_bf, ex_bf, offsets, counts);

    // D5: out = combine(ex) @ w_up^T + outs  (512 blocks)
    k_final<<<dim3(T_TOK / 128, D_MODEL / 64), 256, 0, stream>>>(
        ex_bf, wup_bf, outs, row_of_pair, topk_w, out);
}

// Round 15
// 80.265 us; speedup vs baseline: 1.0346x; 1.0346x over previous
//
#include <hip/hip_runtime.h>
#include <hip/hip_bf16.h>
#include <math.h>

#define T_TOK 4096
#define D_MODEL 1024
#define L_LAT 256
#define H_HID 512
#define E_EXP 8
#define SH_HID 512
#define TOT_EROWS (2 * T_TOK)

typedef __bf16 bf16x8 __attribute__((ext_vector_type(8)));
typedef float f32x4 __attribute__((ext_vector_type(4)));

__device__ __forceinline__ unsigned short f2bf(float f) {
    union { float f; unsigned int u; } c{f};
    unsigned int r = (c.u + 0x7fffu + ((c.u >> 16) & 1u)) >> 16;
    return (unsigned short)r;
}
__device__ __forceinline__ float bf2f(unsigned short u) {
    union { unsigned int u; float f; } c{(unsigned int)u << 16};
    return c.f;
}

__device__ __forceinline__ void gload_lds16(const unsigned short* g, unsigned short* l) {
    __builtin_amdgcn_global_load_lds(
        (const __attribute__((address_space(1))) void*)g,
        (__attribute__((address_space(3))) void*)l,
        16, 0, 0);
}

// 3-bit XOR slot swizzle for BK=64 rows (8 slots x 8 bf16 = 128 B row). Involution.
__device__ __forceinline__ int swz64(int row, int s) {
    return s ^ (row & 7);
}

// ================= D1: fused router+x-cast + small-weight casts (jobs) ===========
// [0,1024): router + x->bf16 cast (1 block = 4 tokens); [1024,2304): wdown/wgs/w1s
__global__ __launch_bounds__(256)
void cast_router_kernel(const float* __restrict__ x, const float* __restrict__ w_router,
                        const float* __restrict__ w_down, const float* __restrict__ wg_s,
                        const float* __restrict__ w1_s,
                        unsigned short* __restrict__ xb, unsigned short* __restrict__ wdb,
                        unsigned short* __restrict__ wgsb, unsigned short* __restrict__ w1sb,
                        int* __restrict__ topk_idx, float* __restrict__ topk_w)
{
    __shared__ float wlds[E_EXP * D_MODEL];   // 32 KB (router job only)
    int bid = blockIdx.x;
    int tid = threadIdx.x;

    if (bid >= 1024) {
        int i = (bid - 1024) * 256 + tid;      // [0, 327680) float4s
        const float* src; unsigned short* dst; int base;
        if      (i < 65536)  { src = w_down; dst = wdb;  base = 0; }
        else if (i < 196608) { src = wg_s;   dst = wgsb; base = 65536; }
        else                 { src = w1_s;   dst = w1sb; base = 196608; }
        int j = (i - base) * 4;
        float4 v = *(const float4*)(src + j);
        ushort4 o = { f2bf(v.x), f2bf(v.y), f2bf(v.z), f2bf(v.w) };
        *(ushort4*)(dst + j) = o;
        return;
    }

    // ---- fused router (exact fp32) + x-cast: wave w handles token bid*4+w ----
    for (int i = tid * 4; i < E_EXP * D_MODEL; i += 256 * 4)
        *(float4*)(wlds + i) = *(const float4*)(w_router + i);
    __syncthreads();

    int wid = tid >> 6, lane = tid & 63;
    int t = bid * 4 + wid;
    const float4* xr4 = (const float4*)(x + (size_t)t * D_MODEL);
    ushort4* xb4 = (ushort4*)(xb + (size_t)t * D_MODEL);
    const float4* wl4 = (const float4*)wlds;

    float acc[E_EXP];
#pragma unroll
    for (int e = 0; e < E_EXP; ++e) acc[e] = 0.f;
#pragma unroll
    for (int j = 0; j < 4; ++j) {
        int f = lane + 64 * j;
        float4 v = xr4[f];
        ushort4 o = { f2bf(v.x), f2bf(v.y), f2bf(v.z), f2bf(v.w) };
        xb4[f] = o;
#pragma unroll
        for (int e = 0; e < E_EXP; ++e) {
            float4 w = wl4[e * 256 + f];
            acc[e] += v.x * w.x + v.y * w.y + v.z * w.z + v.w * w.w;
        }
    }
#pragma unroll
    for (int e = 0; e < E_EXP; ++e)
        for (int off = 32; off > 0; off >>= 1)
            acc[e] += __shfl_xor(acc[e], off, 64);
    if (lane == 0) {
        int i0 = 0; float v0 = acc[0];
#pragma unroll
        for (int e = 1; e < E_EXP; ++e) if (acc[e] > v0) { v0 = acc[e]; i0 = e; }
        int i1 = -1; float v1 = -INFINITY;
#pragma unroll
        for (int e = 0; e < E_EXP; ++e) if (e != i0 && acc[e] > v1) { v1 = acc[e]; i1 = e; }
        float e1 = expf(v1 - v0);
        topk_idx[2 * t] = i0; topk_idx[2 * t + 1] = i1;
        topk_w[2 * t] = 1.f / (1.f + e1);
        topk_w[2 * t + 1] = e1 / (1.f + e1);
    }
}

// ================= bucket body (deterministic, no atomics; 256 threads) =========
__device__ void bucket_body(const int* __restrict__ topk_idx,
                            int* __restrict__ counts, int* __restrict__ offsets,
                            int* __restrict__ tok_of_row, int* __restrict__ row_of_pair,
                            int* sb)
{
    int* s_wavecnt  = sb;        // [4][8]
    int* s_wavebase = sb + 32;   // [4][8]
    int* s_tot      = sb + 64;   // [8]
    int* s_off      = sb + 72;   // [8]
    int tid = threadIdx.x, wave = tid >> 6, lane = tid & 63;
    int base_i = tid * 32;       // 8192 items / 256 threads

    int cnt[E_EXP];
#pragma unroll
    for (int e = 0; e < E_EXP; ++e) cnt[e] = 0;
#pragma unroll
    for (int j = 0; j < 32; ++j) {
        int e = topk_idx[base_i + j];
#pragma unroll
        for (int q = 0; q < E_EXP; ++q) cnt[q] += (e == q) ? 1 : 0;
    }
    int excl[E_EXP];
#pragma unroll
    for (int e = 0; e < E_EXP; ++e) {
        int v = cnt[e];
#pragma unroll
        for (int off = 1; off < 64; off <<= 1) {
            int u = __shfl_up(v, off, 64);
            v += (lane >= off) ? u : 0;
        }
        excl[e] = v - cnt[e];
        if (lane == 63) s_wavecnt[wave * 8 + e] = v;
    }
    __syncthreads();
    if (tid < E_EXP) {
        int tot = 0;
        for (int w = 0; w < 4; ++w) tot += s_wavecnt[w * 8 + tid];
        s_tot[tid] = tot;
        counts[tid] = tot;
    }
    __syncthreads();
    if (tid == 0) {
        int off = 0;
        for (int e = 0; e < E_EXP; ++e) { s_off[e] = off; offsets[e] = off; off += s_tot[e]; }
    }
    __syncthreads();
    if (tid < E_EXP) {
        int run = s_off[tid];
        for (int w = 0; w < 4; ++w) { s_wavebase[w * 8 + tid] = run; run += s_wavecnt[w * 8 + tid]; }
    }
    __syncthreads();
    int tb[E_EXP];
#pragma unroll
    for (int e = 0; e < E_EXP; ++e) tb[e] = s_wavebase[wave * 8 + e] + excl[e];
#pragma unroll
    for (int j = 0; j < 32; ++j) {
        int item = base_i + j;
        int e = topk_idx[item];
        int p = 0;
#pragma unroll
        for (int q = 0; q < E_EXP; ++q) if (e == q) { p = tb[q]; tb[q] = p + 1; }
        tok_of_row[p] = item >> 1;
        row_of_pair[item] = p;
    }
}

// ================= proven BK=64 BN=64 GEMM tile body (dual-capable) =============
// OUT_MODE: 0 = f32 store, 1 = bf16 store
template<bool DUAL, bool SILU, bool EXPERT, bool GATHER, int OUT_MODE>
__device__ void gemm_tile(unsigned short* As, unsigned short* Bs0, unsigned short* Bs1,
                          int m0, int n0, int e,
                          const unsigned short* __restrict__ A,
                          const unsigned short* __restrict__ B0g,
                          const unsigned short* __restrict__ B1g,
                          void* __restrict__ Cv,
                          int M, int K, int ldc,
                          const int* __restrict__ tok_of_row,
                          const int* __restrict__ offsets,
                          const int* __restrict__ counts,
                          long strideB)
{
    int m_base = EXPERT ? offsets[e] : 0;
    int m_count = EXPERT ? counts[e] : M;
    if (m0 >= m_count) return;   // block-uniform

    const unsigned short* B0 = B0g + (EXPERT ? (size_t)e * strideB : 0);
    const unsigned short* B1 = DUAL ? (B1g + (EXPERT ? (size_t)e * strideB : 0)) : nullptr;

    int tid = threadIdx.x;
    int r8 = tid >> 3, slot = tid & 7;

    const unsigned short* aptr[4];
#pragma unroll
    for (int r = 0; r < 4; ++r) {
        int rl = r * 32 + r8;
        int mrow = m0 + rl;
        if (mrow >= m_count) mrow = m_count - 1;      // clamp (epilogue masks)
        long grow;
        if (GATHER)      grow = tok_of_row[m_base + mrow];
        else if (EXPERT) grow = m_base + mrow;
        else             grow = mrow;
        aptr[r] = A + (size_t)grow * K + swz64(rl, slot) * 8;
    }
    const unsigned short* bptr0[2];
    const unsigned short* bptr1[2];
#pragma unroll
    for (int r = 0; r < 2; ++r) {
        int rl = r * 32 + r8;
        int gs = swz64(rl, slot) * 8;
        bptr0[r] = B0 + (size_t)(n0 + rl) * K + gs;
        if (DUAL) bptr1[r] = B1 + (size_t)(n0 + rl) * K + gs;
    }
    unsigned short* As_dst  = As  + tid * 8;
    unsigned short* Bs0_dst = Bs0 + tid * 8;
    unsigned short* Bs1_dst = DUAL ? (Bs1 + tid * 8) : nullptr;

    int wave = tid >> 6, lane = tid & 63;
    int wm0 = (wave >> 1) * 64, wn0 = (wave & 1) * 32;
    int l15 = lane & 15, kg = lane >> 4;

    f32x4 acc0[4][2] = {};
    f32x4 acc1[DUAL ? 4 : 1][DUAL ? 2 : 1] = {};

    for (int k0 = 0; k0 < K; k0 += 64) {
#pragma unroll
        for (int r = 0; r < 4; ++r)
            gload_lds16(aptr[r] + k0, As_dst + r * 2048);
#pragma unroll
        for (int r = 0; r < 2; ++r) {
            gload_lds16(bptr0[r] + k0, Bs0_dst + r * 2048);
            if constexpr (DUAL) gload_lds16(bptr1[r] + k0, Bs1_dst + r * 2048);
        }
        __syncthreads();

        bf16x8 af[2][4];
#pragma unroll
        for (int kh = 0; kh < 2; ++kh)
#pragma unroll
            for (int mf = 0; mf < 4; ++mf) {
                int row = wm0 + mf * 16 + l15;
                af[kh][mf] = *reinterpret_cast<const bf16x8*>(As + row * 64 + swz64(row, kh * 4 + kg) * 8);
            }
        bf16x8 bf0[2][2], bf1[2][2];
#pragma unroll
        for (int kh = 0; kh < 2; ++kh)
#pragma unroll
            for (int nf = 0; nf < 2; ++nf) {
                int row = wn0 + nf * 16 + l15;
                bf0[kh][nf] = *reinterpret_cast<const bf16x8*>(Bs0 + row * 64 + swz64(row, kh * 4 + kg) * 8);
                if constexpr (DUAL)
                    bf1[kh][nf] = *reinterpret_cast<const bf16x8*>(Bs1 + row * 64 + swz64(row, kh * 4 + kg) * 8);
            }
#pragma unroll
        for (int kh = 0; kh < 2; ++kh)
#pragma unroll
            for (int mf = 0; mf < 4; ++mf)
#pragma unroll
                for (int nf = 0; nf < 2; ++nf) {
                    acc0[mf][nf] = __builtin_amdgcn_mfma_f32_16x16x32_bf16(af[kh][mf], bf0[kh][nf], acc0[mf][nf], 0, 0, 0);
                    if constexpr (DUAL)
                        acc1[mf][nf] = __builtin_amdgcn_mfma_f32_16x16x32_bf16(af[kh][mf], bf1[kh][nf], acc1[mf][nf], 0, 0, 0);
                }
        __syncthreads();
    }

#pragma unroll
    for (int mf = 0; mf < 4; ++mf) {
#pragma unroll
        for (int r4 = 0; r4 < 4; ++r4) {
            int mrow = m0 + wm0 + mf * 16 + kg * 4 + r4;
            if (mrow >= m_count) continue;
            size_t crow = (size_t)((EXPERT ? m_base : 0) + mrow) * ldc + n0 + wn0;
#pragma unroll
            for (int nf = 0; nf < 2; ++nf) {
                float v = acc0[mf][nf][r4];
                if constexpr (SILU) {
                    float g = v;
                    float a = acc1[mf][nf][r4];
                    v = (g / (1.f + expf(-g))) * a;
                }
                int col = nf * 16 + l15;
                if constexpr (OUT_MODE == 1) ((unsigned short*)Cv)[crow + col] = f2bf(v);
                else                         ((float*)Cv)[crow + col] = v;
            }
        }
    }
}

// ================= 128x128 non-dual tile (BK=64), gload staging ==================
// OUT_MODE: 0 = f32 store, 1 = bf16 store
template<bool EXPERT, int OUT_MODE>
__device__ void gemm_tile_n128(unsigned short* SM,
                               int m0, int n0, int e,
                               const unsigned short* __restrict__ A,
                               const unsigned short* __restrict__ B0g,
                               void* __restrict__ Cv,
                               int M, int K, int ldc,
                               const int* __restrict__ offsets,
                               const int* __restrict__ counts,
                               long strideB)
{
    unsigned short* As = SM;              // 128*64
    unsigned short* Bs = SM + 128 * 64;   // 128*64

    int m_base = EXPERT ? offsets[e] : 0;
    int m_count = EXPERT ? counts[e] : M;
    if (m0 >= m_count) return;

    const unsigned short* B0 = B0g + (EXPERT ? (size_t)e * strideB : 0);

    int tid = threadIdx.x;
    int r8 = tid >> 3, slot = tid & 7;

    const unsigned short* aptr[4];
#pragma unroll
    for (int r = 0; r < 4; ++r) {
        int rl = r * 32 + r8;
        int mrow = m0 + rl;
        if (mrow >= m_count) mrow = m_count - 1;
        long grow = EXPERT ? (long)(m_base + mrow) : (long)mrow;
        aptr[r] = A + (size_t)grow * K + swz64(rl, slot) * 8;
    }
    const unsigned short* bptr[4];
#pragma unroll
    for (int r = 0; r < 4; ++r) {
        int rl = r * 32 + r8;
        bptr[r] = B0 + (size_t)(n0 + rl) * K + swz64(rl, slot) * 8;
    }
    unsigned short* As_dst = As + tid * 8;
    unsigned short* Bs_dst = Bs + tid * 8;

    int wave = tid >> 6, lane = tid & 63;
    int wm0 = (wave >> 1) * 64, wn0 = (wave & 1) * 64;
    int l15 = lane & 15, kg = lane >> 4;

    f32x4 acc[4][4] = {};

    for (int k0 = 0; k0 < K; k0 += 64) {
#pragma unroll
        for (int r = 0; r < 4; ++r)
            gload_lds16(aptr[r] + k0, As_dst + r * 2048);
#pragma unroll
        for (int r = 0; r < 4; ++r)
            gload_lds16(bptr[r] + k0, Bs_dst + r * 2048);
        __syncthreads();

        bf16x8 af[2][4], bfr[2][4];
#pragma unroll
        for (int kh = 0; kh < 2; ++kh) {
#pragma unroll
            for (int mf = 0; mf < 4; ++mf) {
                int row = wm0 + mf * 16 + l15;
                af[kh][mf] = *reinterpret_cast<const bf16x8*>(As + row * 64 + swz64(row, kh * 4 + kg) * 8);
            }
#pragma unroll
            for (int nf = 0; nf < 4; ++nf) {
                int row = wn0 + nf * 16 + l15;
                bfr[kh][nf] = *reinterpret_cast<const bf16x8*>(Bs + row * 64 + swz64(row, kh * 4 + kg) * 8);
            }
        }
#pragma unroll
        for (int kh = 0; kh < 2; ++kh)
#pragma unroll
            for (int mf = 0; mf < 4; ++mf)
#pragma unroll
                for (int nf = 0; nf < 4; ++nf)
                    acc[mf][nf] = __builtin_amdgcn_mfma_f32_16x16x32_bf16(af[kh][mf], bfr[kh][nf], acc[mf][nf], 0, 0, 0);
        __syncthreads();
    }

#pragma unroll
    for (int mf = 0; mf < 4; ++mf) {
#pragma unroll
        for (int r4 = 0; r4 < 4; ++r4) {
            int mrow = m0 + wm0 + mf * 16 + kg * 4 + r4;
            if (mrow >= m_count) continue;
            size_t crow = (size_t)((EXPERT ? m_base : 0) + mrow) * ldc + n0 + wn0;
#pragma unroll
            for (int nf = 0; nf < 4; ++nf) {
                float v = acc[mf][nf][r4];
                int col = nf * 16 + l15;
                if constexpr (OUT_MODE == 1) ((unsigned short*)Cv)[crow + col] = f2bf(v);
                else                         ((float*)Cv)[crow + col] = v;
            }
        }
    }
}

// ================= D2: GEMM1 + GEMM2 + bucket + big-weight casts (jobs) ==========
// (round-13 ordering: GEMM1 y<4 first, then GEMM2)
__global__ __launch_bounds__(256)
void k_main(const unsigned short* __restrict__ x_bf,
            const unsigned short* __restrict__ wdown_bf,
            const unsigned short* __restrict__ wgs_bf,
            const unsigned short* __restrict__ w1s_bf,
            const float* __restrict__ wg_e, const float* __restrict__ w1_e,
            const float* __restrict__ w2_e,
            const float* __restrict__ w_up, const float* __restrict__ w2_s,
            unsigned short* __restrict__ lat_bf,
            unsigned short* __restrict__ hs,
            unsigned short* __restrict__ wge_bf, unsigned short* __restrict__ w1e_bf,
            unsigned short* __restrict__ w2e_bf, unsigned short* __restrict__ wup_bf,
            unsigned short* __restrict__ w2s_bf,
            const int* __restrict__ topk_idx,
            int* __restrict__ counts, int* __restrict__ offsets,
            int* __restrict__ tok_of_row, int* __restrict__ row_of_pair)
{
    __shared__ __align__(16) unsigned short SM[16384];   // 32 KB
    unsigned short* As  = SM;
    unsigned short* Bs0 = SM + 8192;
    unsigned short* Bs1 = SM + 12288;

    int bid = blockIdx.x;
    int tid = threadIdx.x;

    if (bid == 384) {
        bucket_body(topk_idx, counts, offsets, tok_of_row, row_of_pair, (int*)SM);
        return;
    }
    if (bid > 384) {
        int i = (bid - 385) * 256 + tid;       // [0, 983040) float4s
        const float* src; unsigned short* dst; int base;
        if      (i < 262144) { src = wg_e; dst = wge_bf; base = 0; }
        else if (i < 524288) { src = w1_e; dst = w1e_bf; base = 262144; }
        else if (i < 786432) { src = w2_e; dst = w2e_bf; base = 524288; }
        else if (i < 851968) { src = w_up; dst = wup_bf; base = 786432; }
        else                 { src = w2_s; dst = w2s_bf; base = 851968; }
        int j = (i - base) * 4;
        float4 v = *(const float4*)(src + j);
        ushort4 o = { f2bf(v.x), f2bf(v.y), f2bf(v.z), f2bf(v.w) };
        *(ushort4*)(dst + j) = o;
        return;
    }

    int xq = bid & 31, y = bid >> 5;
    if (y < 4) {
        gemm_tile<false, false, false, false, 1>(As, Bs0, Bs1, xq * 128, y * 64, 0,
            x_bf, wdown_bf, nullptr, lat_bf, T_TOK, D_MODEL, L_LAT,
            nullptr, nullptr, nullptr, 0);
    } else {
        gemm_tile<true, true, false, false, 1>(As, Bs0, Bs1, xq * 128, (y - 4) * 64, 0,
            x_bf, wgs_bf, w1s_bf, hs, T_TOK, D_MODEL, SH_HID,
            nullptr, nullptr, nullptr, 0);
    }
}

// ================= D3: expert-up (BN=64 dual, bucketed) + shared out (BN=128) ====
// (round-13 ordering: expert-up first, shared-out tail)
__global__ __launch_bounds__(256)
void k_exp_sh(const unsigned short* __restrict__ lat_bf,
              const unsigned short* __restrict__ wge_bf,
              const unsigned short* __restrict__ w1e_bf,
              const unsigned short* __restrict__ hs,
              const unsigned short* __restrict__ w2s_bf,
              unsigned short* __restrict__ hbuf_bf,
              unsigned short* __restrict__ outs,
              const int* __restrict__ tok_of_row,
              const int* __restrict__ offsets,
              const int* __restrict__ counts)
{
    __shared__ __align__(16) unsigned short SM[16384];   // 32 KB
    int bid = blockIdx.x;
    if (bid < 4096) {
        int xq = bid >> 6, e = (bid >> 3) & 7, y = bid & 7;
        gemm_tile<true, true, true, true, 1>(SM, SM + 8192, SM + 12288,
            xq * 128, y * 64, e,
            lat_bf, wge_bf, w1e_bf, hbuf_bf, 0, L_LAT, H_HID,
            tok_of_row, offsets, counts, (long)H_HID * L_LAT);
    } else {
        int idx = bid - 4096;
        int xq = idx & 31, y = idx >> 5;     // y in [0,8)
        gemm_tile_n128<false, 1>(SM, xq * 128, y * 128, 0,
            hs, w2s_bf, outs, T_TOK, SH_HID, D_MODEL,
            nullptr, nullptr, 0);
    }
}

// ================= D4: expert-down -> ex_bf; grid (n-tile, expert, m-tile) =======
// Real tiles (m-tile < count/128) are contiguous at the front of flat block order.
__global__ __launch_bounds__(256)
void k_expdown(const unsigned short* __restrict__ hbuf_bf,
               const unsigned short* __restrict__ w2e_bf,
               unsigned short* __restrict__ ex_bf,
               const int* __restrict__ offsets,
               const int* __restrict__ counts)
{
    __shared__ __align__(16) unsigned short SM[16384];
    gemm_tile<false, false, true, false, 1>(SM, SM + 8192, SM + 12288,
        blockIdx.z * 128, blockIdx.x * 64, blockIdx.y,
        hbuf_bf, w2e_bf, nullptr, ex_bf, 0, H_HID, L_LAT,
        nullptr, offsets, counts, (long)L_LAT * H_HID);
}

// ================= D5: out = combine(ex)@w_up^T + outs  (BM=128/BN=64) ==========
// A: reg-blend staged (uniform every K-step); B: gload_lds (uniform every K-step)
__global__ __launch_bounds__(256)
void k_final(const unsigned short* __restrict__ ex_bf,
             const unsigned short* __restrict__ wup_bf,
             const unsigned short* __restrict__ outs,
             const int* __restrict__ row_of_pair,
             const float* __restrict__ topk_w,
             float* __restrict__ out)
{
    __shared__ __align__(16) unsigned short As[128 * 64];   // 16 KB
    __shared__ __align__(16) unsigned short Bs[64 * 64];    // 8 KB

    int m0 = blockIdx.x * 128, n0 = blockIdx.y * 64;
    int tid = threadIdx.x;
    int r8 = tid >> 3, slot = tid & 7;

    const unsigned short* aptr[4];
    const unsigned short* a2ptr[4];
    float wa[4], wb[4];
#pragma unroll
    for (int r = 0; r < 4; ++r) {
        int rl = r * 32 + r8;
        int t = m0 + rl;
        int rp0 = row_of_pair[2 * t], rp1 = row_of_pair[2 * t + 1];
        wa[r] = topk_w[2 * t]; wb[r] = topk_w[2 * t + 1];
        int gs = swz64(rl, slot) * 8;
        aptr[r]  = ex_bf + (size_t)rp0 * L_LAT + gs;
        a2ptr[r] = ex_bf + (size_t)rp1 * L_LAT + gs;
    }
    const unsigned short* bptr[2];
#pragma unroll
    for (int r = 0; r < 2; ++r) {
        int rl = r * 32 + r8;
        bptr[r] = wup_bf + (size_t)(n0 + rl) * L_LAT + swz64(rl, slot) * 8;
    }
    unsigned short* As_dst = As + tid * 8;
    unsigned short* Bs_dst = Bs + tid * 8;

    int wave = tid >> 6, lane = tid & 63;
    int wm0 = (wave >> 1) * 64, wn0 = (wave & 1) * 32;
    int l15 = lane & 15, kg = lane >> 4;

    f32x4 acc[4][2] = {};

    for (int k0 = 0; k0 < L_LAT; k0 += 64) {
        // A: reg-blend stage (uniform mechanism every step)
#pragma unroll
        for (int r = 0; r < 4; ++r) {
            ushort4 u0 = *(const ushort4*)(aptr[r] + k0);
            ushort4 u1 = *(const ushort4*)(aptr[r] + k0 + 4);
            ushort4 v0 = *(const ushort4*)(a2ptr[r] + k0);
            ushort4 v1 = *(const ushort4*)(a2ptr[r] + k0 + 4);
            ushort4 lo = { f2bf(wa[r] * bf2f(u0.x) + wb[r] * bf2f(v0.x)),
                           f2bf(wa[r] * bf2f(u0.y) + wb[r] * bf2f(v0.y)),
                           f2bf(wa[r] * bf2f(u0.z) + wb[r] * bf2f(v0.z)),
                           f2bf(wa[r] * bf2f(u0.w) + wb[r] * bf2f(v0.w)) };
            ushort4 hi = { f2bf(wa[r] * bf2f(u1.x) + wb[r] * bf2f(v1.x)),
                           f2bf(wa[r] * bf2f(u1.y) + wb[r] * bf2f(v1.y)),
                           f2bf(wa[r] * bf2f(u1.z) + wb[r] * bf2f(v1.z)),
                           f2bf(wa[r] * bf2f(u1.w) + wb[r] * bf2f(v1.w)) };
            *(ushort4*)(As_dst + r * 2048) = lo;
            *(ushort4*)(As_dst + r * 2048 + 4) = hi;
        }
        // B: gload stage (uniform mechanism every step)
#pragma unroll
        for (int r = 0; r < 2; ++r)
            gload_lds16(bptr[r] + k0, Bs_dst + r * 2048);
        __syncthreads();

        bf16x8 af[2][4], bfr[2][2];
#pragma unroll
        for (int kh = 0; kh < 2; ++kh) {
#pragma unroll
            for (int mf = 0; mf < 4; ++mf) {
                int row = wm0 + mf * 16 + l15;
                af[kh][mf] = *reinterpret_cast<const bf16x8*>(As + row * 64 + swz64(row, kh * 4 + kg) * 8);
            }
#pragma unroll
            for (int nf = 0; nf < 2; ++nf) {
                int row = wn0 + nf * 16 + l15;
                bfr[kh][nf] = *reinterpret_cast<const bf16x8*>(Bs + row * 64 + swz64(row, kh * 4 + kg) * 8);
            }
        }
#pragma unroll
        for (int kh = 0; kh < 2; ++kh)
#pragma unroll
            for (int mf = 0; mf < 4; ++mf)
#pragma unroll
                for (int nf = 0; nf < 2; ++nf)
                    acc[mf][nf] = __builtin_amdgcn_mfma_f32_16x16x32_bf16(af[kh][mf], bfr[kh][nf], acc[mf][nf], 0, 0, 0);
        __syncthreads();
    }

#pragma unroll
    for (int mf = 0; mf < 4; ++mf)
#pragma unroll
        for (int r4 = 0; r4 < 4; ++r4) {
            int mrow = m0 + wm0 + mf * 16 + kg * 4 + r4;
            size_t crow = (size_t)mrow * D_MODEL + n0 + wn0;
#pragma unroll
            for (int nf = 0; nf < 2; ++nf) {
                int col = nf * 16 + l15;
                out[crow + col] = acc[mf][nf][r4] + bf2f(outs[crow + col]);
            }
        }
}

extern "C" void kernel_launch(void* const* d_in, const int* in_sizes, int n_in,
                              void* d_out, int out_size, void* d_ws, size_t ws_size,
                              hipStream_t stream)
{
    const float* x        = (const float*)d_in[0];
    const float* w_router = (const float*)d_in[1];
    const float* w_down   = (const float*)d_in[2];
    const float* w_up     = (const float*)d_in[3];
    const float* w1_e     = (const float*)d_in[4];
    const float* wg_e     = (const float*)d_in[5];
    const float* w2_e     = (const float*)d_in[6];
    const float* w1_s     = (const float*)d_in[7];
    const float* wg_s     = (const float*)d_in[8];
    const float* w2_s     = (const float*)d_in[9];
    float* out = (float*)d_out;

    char* ws = (char*)d_ws;
    size_t off = 0;
    auto alloc = [&](size_t bytes) -> void* {
        void* p = ws + off;
        off += (bytes + 255) & ~(size_t)255;
        return p;
    };
    unsigned short* x_bf    = (unsigned short*)alloc((size_t)T_TOK * D_MODEL * 2);    // 8 MB (alias: hbuf)
    unsigned short* lat_bf  = (unsigned short*)alloc((size_t)T_TOK * L_LAT * 2);      // 2 MB
    unsigned short* hs      = (unsigned short*)alloc((size_t)T_TOK * SH_HID * 2);     // 4 MB
    unsigned short* outs    = (unsigned short*)alloc((size_t)T_TOK * D_MODEL * 2);    // 8 MB
    unsigned short* ex_bf   = (unsigned short*)alloc((size_t)TOT_EROWS * L_LAT * 2);  // 4 MB
    unsigned short* wdown_bf= (unsigned short*)alloc((size_t)L_LAT * D_MODEL * 2);
    unsigned short* wge_bf  = (unsigned short*)alloc((size_t)E_EXP * H_HID * L_LAT * 2);
    unsigned short* w1e_bf  = (unsigned short*)alloc((size_t)E_EXP * H_HID * L_LAT * 2);
    unsigned short* w2e_bf  = (unsigned short*)alloc((size_t)E_EXP * L_LAT * H_HID * 2);
    unsigned short* wgs_bf  = (unsigned short*)alloc((size_t)SH_HID * D_MODEL * 2);
    unsigned short* w1s_bf  = (unsigned short*)alloc((size_t)SH_HID * D_MODEL * 2);
    unsigned short* wup_bf  = (unsigned short*)alloc((size_t)D_MODEL * L_LAT * 2);
    unsigned short* w2s_bf  = (unsigned short*)alloc((size_t)D_MODEL * SH_HID * 2);
    int*   topk_idx    = (int*)alloc(T_TOK * 2 * 4);
    float* topk_w      = (float*)alloc(T_TOK * 2 * 4);
    int*   tok_of_row  = (int*)alloc(T_TOK * 2 * 4);
    int*   row_of_pair = (int*)alloc(T_TOK * 2 * 4);
    int*   counts      = (int*)alloc(E_EXP * 4);
    int*   offsets     = (int*)alloc(E_EXP * 4);
    unsigned short* hbuf_bf = x_bf;   // alias: x_bf dead after D2

    // D1: fused router+x-cast + small-weight casts (2304 blocks)
    cast_router_kernel<<<2304, 256, 0, stream>>>(
        x, w_router, w_down, wg_s, w1_s,
        x_bf, wdown_bf, wgs_bf, w1s_bf, topk_idx, topk_w);

    // D2: GEMM1 + GEMM2 + bucket + big-weight casts (round-13 ordering)
    k_main<<<4225, 256, 0, stream>>>(
        x_bf, wdown_bf, wgs_bf, w1s_bf, wg_e, w1_e, w2_e, w_up, w2_s,
        lat_bf, hs, wge_bf, w1e_bf, w2e_bf, wup_bf, w2s_bf,
        topk_idx, counts, offsets, tok_of_row, row_of_pair);

    // D3: expert-up (gathered buckets) + shared out-GEMM -> outs (round-13 ordering)
    k_exp_sh<<<4352, 256, 0, stream>>>(
        lat_bf, wge_bf, w1e_bf, hs, w2s_bf, hbuf_bf, outs,
        tok_of_row, offsets, counts);

    // D4: expert-down: ex_bf = hbuf @ w2_e^T (real tiles front-packed)
    k_expdown<<<dim3(L_LAT / 64, E_EXP, TOT_EROWS / 128), 256, 0, stream>>>(
        hbuf_bf, w2e_bf, ex_bf, offsets, counts);

    // D5: out = combine(ex) @ w_up^T + outs  (512 blocks)
    k_final<<<dim3(T_TOK / 128, D_MODEL / 64), 256, 0, stream>>>(
        ex_bf, wup_bf, outs, row_of_pair, topk_w, out);
}